// Round 5
// baseline (94.987 us; speedup 1.0000x reference)
//
#include <hip/hip_runtime.h>
#include <math.h>

#define NPART 8192
#define R2c   0.0025f     /* RADIUS^2 (float32(0.05^2)) */
#define CR2c  0.01f       /* (2*RADIUS)^2 */
#define ACCS  0.005f
#define MAXV  0.05f
#define EPSV  1e-06f
#define NB1D  20          /* bins per axis, width 0.1 over [-1,1] */
#define NBINS 400
#define NPREP 32          /* prep blocks (per-block histograms) */
#define SWBLK 2048        /* sweep blocks: 4 waves = 4 sorted slots each */
#define OUT_SCALARS 57344 /* offset of the 6 scalar outputs in d_out */

#define WRED(v) do { \
    v += __shfl_xor(v, 32); v += __shfl_xor(v, 16); v += __shfl_xor(v, 8); \
    v += __shfl_xor(v, 4);  v += __shfl_xor(v, 2);  v += __shfl_xor(v, 1); \
  } while (0)

// ---------------------------------------------------------------- K1 ------
// prep + per-block histogram. Per row: 32B record {px,py,y0,y1|y2,y3,ci,orig}
// + bin id. Each block LDS-histograms its 256 rows and writes the transposed
// per-block counts bhistT[bin*32+blk] (EVERY entry written -> no zero pass,
// no global atomics, fully deterministic).
__global__ __launch_bounds__(256) void prep_kernel(
    const float* __restrict__ x, const float* __restrict__ wn,
    float4* __restrict__ rec, int* __restrict__ binid,
    int* __restrict__ bhistT)
{
  __shared__ int h[NBINS];
  const int t = threadIdx.x;
  h[t] = 0;
  if (t + 256 < NBINS) h[t + 256] = 0;
  __syncthreads();

  const int i = blockIdx.x * 256 + t;
  const float* xi = x + i * 7;
  float v0 = xi[0], v1 = xi[1], v2 = xi[2], v3 = xi[3];
  float v4 = xi[4], v5 = xi[5], v6 = xi[6];
  float ci = (v4 > 0.5f) ? 1.0f : 0.0f;
  float y[4];
#pragma unroll
  for (int c = 0; c < 4; ++c) {
    float s = v0 * wn[c];
    s += v1 * wn[4 + c];
    s += v2 * wn[8 + c];
    s += v3 * wn[12 + c];
    s += v4 * wn[16 + c];
    s += v5 * wn[20 + c];
    s += v6 * wn[24 + c];
    y[c] = s;
  }
  int bx = (int)floorf((v0 + 1.0f) * 10.0f); bx = bx < 0 ? 0 : (bx > 19 ? 19 : bx);
  int by = (int)floorf((v1 + 1.0f) * 10.0f); by = by < 0 ? 0 : (by > 19 ? 19 : by);
  const int bid = by * NB1D + bx;
  binid[i] = bid;
  rec[i * 2]     = make_float4(v0, v1, y[0], y[1]);
  rec[i * 2 + 1] = make_float4(y[2], y[3], ci, __int_as_float(i));
  atomicAdd(&h[bid], 1); /* LDS atomic, order-independent count */
  __syncthreads();

  bhistT[t * NPREP + blockIdx.x] = h[t];
  if (t + 256 < NBINS) bhistT[(t + 256) * NPREP + blockIdx.x] = h[t + 256];
}

// ---------------------------------------------------------------- K2 ------
// scan + stable scatter, one wave per bin (100 blocks x 4 waves). Each wave
// derives binstart[b] itself from bhistT (int4 loads + wave reduce), writes
// binstart, then scans binid[] in index order; ballot + prefix-popcount gives
// the stable rank. Deterministic. Also resets K3's finisher counter.
__global__ __launch_bounds__(256) void scatter_kernel(
    const int* __restrict__ binid, const int* __restrict__ bhistT,
    const float4* __restrict__ rec, float4* __restrict__ srec,
    int* __restrict__ binstart, int* __restrict__ counter)
{
  const int lane = threadIdx.x & 63, wave = threadIdx.x >> 6;
  const int b = blockIdx.x * 4 + wave;
  if (blockIdx.x == 0 && threadIdx.x == 0) counter[0] = 0;

  int accLT = 0, accEQ = 0;
#pragma unroll
  for (int k = 0; k < 7; ++k) {
    int idx = k * 64 + lane;
    if (idx < NBINS && idx <= b) {
      const int4* hp = (const int4*)(bhistT + idx * NPREP);
      int s = 0;
#pragma unroll
      for (int q = 0; q < NPREP / 4; ++q) {
        int4 v = hp[q];
        s += v.x + v.y + v.z + v.w;
      }
      if (idx < b) accLT += s; else accEQ = s;
    }
  }
  WRED(accLT); WRED(accEQ);
  if (lane == 0) {
    binstart[b] = accLT;
    if (b == NBINS - 1) binstart[NBINS] = accLT + accEQ;
  }
  if (accEQ == 0) return;

  int rank = accLT;
  for (int c = 0; c < NPART; c += 256) {
    int i0 = binid[c + lane];
    int i1 = binid[c + 64 + lane];
    int i2 = binid[c + 128 + lane];
    int i3 = binid[c + 192 + lane];
#define STEP(II, CC) { \
      unsigned long long m = __ballot((II) == b); \
      if ((II) == b) { \
        int my = rank + __popcll(m & ((1ull << lane) - 1ull)); \
        srec[my * 2]     = rec[((CC) + lane) * 2]; \
        srec[my * 2 + 1] = rec[((CC) + lane) * 2 + 1]; \
      } \
      rank += __popcll(m); }
    STEP(i0, c) STEP(i1, c + 64) STEP(i2, c + 128) STEP(i3, c + 192)
#undef STEP
  }
}

// ---------------------------------------------------------------- K3 ------
// sweep + fused scalar reduction. One wave per sorted slot (8192 waves,
// co-resident at 8 waves/SIMD). Candidates = 3 contiguous sorted segments
// (3x3 bins, bounds prefetched together). Self excluded via index compare.
// dist2 in the reference's non-contracted mul/mul/add form. Last block to
// finish (atomic ticket) reduces the 2048x6 partials in FIXED lane-strided
// order -> bitwise deterministic, same order as the old reduce kernel.
__global__ __launch_bounds__(256, 8) void sweep_kernel(
    const float* __restrict__ x, const float* __restrict__ wself,
    const float* __restrict__ bvec, const int* __restrict__ binstart,
    const float4* __restrict__ srec, float* __restrict__ out,
    float* __restrict__ partials, int* __restrict__ counter)
{
  __shared__ float s_scal[4][6];
  __shared__ int s_last;
  const int lane = threadIdx.x & 63, wave = threadIdx.x >> 6;
  const int s = blockIdx.x * 4 + wave;
  const float4 r0 = srec[s * 2];
  const float4 r1 = srec[s * 2 + 1];
  const float px = r0.x, py = r0.y, ci = r1.z;
  const int orig = __float_as_int(r1.w);
  int bx = (int)floorf((px + 1.0f) * 10.0f); bx = bx < 0 ? 0 : (bx > 19 ? 19 : bx);
  int by = (int)floorf((py + 1.0f) * 10.0f); by = by < 0 ? 0 : (by > 19 ? 19 : by);
  const int xlo = (bx > 0) ? bx - 1 : 0, xhi = (bx < 19) ? bx + 1 : 19;
  const int rm = by - 1, rp = by + 1;
  const int b0 = (rm >= 0) ? binstart[rm * NB1D + xlo] : 0;
  const int e0 = (rm >= 0) ? binstart[rm * NB1D + xhi + 1] : 0;
  const int b1 = binstart[by * NB1D + xlo];
  const int e1 = binstart[by * NB1D + xhi + 1];
  const int b2 = (rp < NB1D) ? binstart[rp * NB1D + xlo] : 0;
  const int e2 = (rp < NB1D) ? binstart[rp * NB1D + xhi + 1] : 0;

  float nsx = 0.f, nsy = 0.f, nsz = 0.f, nsw = 0.f;
  float cntR = 0.f, cnbR = 0.f, consCR = 0.f;

#pragma unroll
  for (int seg = 0; seg < 3; ++seg) {
    const int beg = (seg == 0) ? b0 : (seg == 1) ? b1 : b2;
    const int end = (seg == 0) ? e0 : (seg == 1) ? e1 : e2;
    for (int c = beg; c < end; c += 64) {
      int idx = c + lane;
      bool inr = idx < end;
      int ia = inr ? idx : beg;
      float4 a0 = srec[ia * 2];
      float4 a1 = srec[ia * 2 + 1];
      float dx = __fsub_rn(px, a0.x), dy = __fsub_rn(py, a0.y);
      float d2 = __fadd_rn(__fmul_rn(dx, dx), __fmul_rn(dy, dy));
      bool valid = inr && (__float_as_int(a1.w) != orig);
      bool inCR = valid && (d2 < CR2c);
      bool inR  = valid && (d2 < R2c);
      float cj = a1.z;
      consCR += inCR ? cj : 0.f;
      cntR += inR ? 1.f : 0.f;
      cnbR += inR ? cj : 0.f;
      nsx += inR ? a0.z : 0.f;
      nsy += inR ? a0.w : 0.f;
      nsz += inR ? a1.x : 0.f;
      nsw += inR ? a1.y : 0.f;
    }
  }

  WRED(nsx); WRED(nsy); WRED(nsz); WRED(nsw);
  WRED(cntR); WRED(cnbR); WRED(consCR);

  if (lane == 0) {
    const float* xi = x + orig * 7;
    float vx = xi[2], vy = xi[3], typ = xi[4], x5 = xi[5], x6 = xi[6];
    float h0 = bvec[0] + px * wself[0] + py * wself[4] + vx * wself[8] +
               vy * wself[12] + typ * wself[16] + x5 * wself[20] +
               x6 * wself[24] + nsx;
    float h1 = bvec[1] + px * wself[1] + py * wself[5] + vx * wself[9] +
               vy * wself[13] + typ * wself[17] + x5 * wself[21] +
               x6 * wself[25] + nsy;
    float h2 = bvec[2] + px * wself[2] + py * wself[6] + vx * wself[10] +
               vy * wself[14] + typ * wself[18] + x5 * wself[22] +
               x6 * wself[26] + nsz;
    float h3 = bvec[3] + px * wself[3] + py * wself[7] + vx * wself[11] +
               vy * wself[15] + typ * wself[19] + x5 * wself[23] +
               x6 * wself[27] + nsw;
    float scm = ACCS * ci;
    h0 *= scm; h1 *= scm; h2 *= scm; h3 *= scm;
    float nvx = fminf(fmaxf(vx + h0, -MAXV), MAXV);
    float nvy = fminf(fmaxf(vy + h1, -MAXV), MAXV);
    float npx = px + nvx, npy = py + nvy;
    float border = 0.f;
    float ax = fabsf(npx), ay = fabsf(npy);
    if (ax > 1.0f) border += logf(ax + EPSV);
    if (ay > 1.0f) border += logf(ay + EPSV);
    bool dead = (ci > 0.5f) && (cnbR < 2.5f);
    bool consumed = (ci < 0.5f) && (consCR > 4.5f);
    float keep = (dead || consumed) ? 0.f : 1.f;
    float* orow = out + (size_t)orig * 7;
    orow[0] = npx * keep; orow[1] = npy * keep;
    orow[2] = nvx * keep; orow[3] = nvy * keep;
    orow[4] = typ * keep; orow[5] = h2 * keep; orow[6] = h3 * keep;
    s_scal[wave][0] = fabsf(nvx);
    s_scal[wave][1] = fabsf(nvy);
    s_scal[wave][2] = border;
    s_scal[wave][3] = consumed ? 1.f : 0.f;
    s_scal[wave][4] = dead ? 1.f : 0.f;
    s_scal[wave][5] = cntR - cnbR;
  }
  __syncthreads();
  if (threadIdx.x == 0) {
#pragma unroll
    for (int k = 0; k < 6; ++k)
      partials[blockIdx.x * 6 + k] =
          s_scal[0][k] + s_scal[1][k] + s_scal[2][k] + s_scal[3][k];
    __threadfence();
    int old = atomicAdd(counter, 1);
    s_last = (old == SWBLK - 1) ? 1 : 0;
  }
  __syncthreads();
  if (s_last) {
    __threadfence();
    for (int m = wave; m < 6; m += 4) {
      float acc = 0.f;
      for (int bidx = lane; bidx < SWBLK; bidx += 64)
        acc += partials[bidx * 6 + m];
      WRED(acc);
      if (lane == 0)
        out[OUT_SCALARS + m] = (m < 2) ? acc * (1.0f / 8192.0f) : acc;
    }
  }
}

// ------------------------------------------------------------- launch -----
extern "C" void kernel_launch(void* const* d_in, const int* in_sizes, int n_in,
                              void* d_out, int out_size, void* d_ws, size_t ws_size,
                              hipStream_t stream)
{
  const float* x      = (const float*)d_in[0];
  const float* wself  = (const float*)d_in[1];
  const float* wneigh = (const float*)d_in[2];
  const float* bvec   = (const float*)d_in[3];
  float* out = (float*)d_out;
  float* ws  = (float*)d_ws;

  float4* rec   = (float4*)ws;                      /* 8N floats          */
  float4* srec  = (float4*)(ws + 8 * NPART);        /* 8N floats          */
  int* binid    = (int*)(ws + 16 * NPART);          /* N ints             */
  int* bhistT   = (int*)(ws + 17 * NPART);          /* NBINS*NPREP ints   */
  int* binstart = bhistT + NBINS * NPREP;           /* NBINS+1 ints       */
  int* counter  = binstart + NBINS + 1;             /* 1 int              */
  float* partials = (float*)(counter + 63);         /* SWBLK*6 floats     */

  hipLaunchKernelGGL(prep_kernel, dim3(NPART / 256), dim3(256), 0, stream,
                     x, wneigh, rec, binid, bhistT);
  hipLaunchKernelGGL(scatter_kernel, dim3(NBINS / 4), dim3(256), 0, stream,
                     binid, bhistT, rec, srec, binstart, counter);
  hipLaunchKernelGGL(sweep_kernel, dim3(SWBLK), dim3(256), 0, stream,
                     x, wself, bvec, binstart, srec, out, partials, counter);
}

// Round 6
// 49.348 us; speedup vs baseline: 1.9249x; 1.9249x over previous
//
#include <hip/hip_runtime.h>
#include <math.h>

#define NPART 8192
#define R2c   0.0025f     /* RADIUS^2 (float32(0.05^2)) */
#define CR2c  0.01f       /* (2*RADIUS)^2 */
#define ACCS  0.005f
#define MAXV  0.05f
#define EPSV  1e-06f
#define NB1D  20          /* bins per axis, width 0.1 over [-1,1] */
#define NBINS 400
#define NPREP 32          /* prep blocks (per-block histograms) */
#define SWBLK 2048        /* sweep blocks: 4 waves = 4 sorted slots each */
#define OUT_SCALARS 57344 /* offset of the 6 scalar outputs in d_out */

#define WRED(v) do { \
    v += __shfl_xor(v, 32); v += __shfl_xor(v, 16); v += __shfl_xor(v, 8); \
    v += __shfl_xor(v, 4);  v += __shfl_xor(v, 2);  v += __shfl_xor(v, 1); \
  } while (0)

// ---------------------------------------------------------------- K1 ------
// prep + per-block histogram. Per row: 32B record {px,py,y0,y1|y2,y3,ci,orig}
// + bin id. Each block LDS-histograms its 256 rows and writes the transposed
// per-block counts bhistT[bin*32+blk] (EVERY entry written -> no zero pass,
// no global atomics, fully deterministic).
__global__ __launch_bounds__(256) void prep_kernel(
    const float* __restrict__ x, const float* __restrict__ wn,
    float4* __restrict__ rec, int* __restrict__ binid,
    int* __restrict__ bhistT)
{
  __shared__ int h[NBINS];
  const int t = threadIdx.x;
  h[t] = 0;
  if (t + 256 < NBINS) h[t + 256] = 0;
  __syncthreads();

  const int i = blockIdx.x * 256 + t;
  const float* xi = x + i * 7;
  float v0 = xi[0], v1 = xi[1], v2 = xi[2], v3 = xi[3];
  float v4 = xi[4], v5 = xi[5], v6 = xi[6];
  float ci = (v4 > 0.5f) ? 1.0f : 0.0f;
  float y[4];
#pragma unroll
  for (int c = 0; c < 4; ++c) {
    float s = v0 * wn[c];
    s += v1 * wn[4 + c];
    s += v2 * wn[8 + c];
    s += v3 * wn[12 + c];
    s += v4 * wn[16 + c];
    s += v5 * wn[20 + c];
    s += v6 * wn[24 + c];
    y[c] = s;
  }
  int bx = (int)floorf((v0 + 1.0f) * 10.0f); bx = bx < 0 ? 0 : (bx > 19 ? 19 : bx);
  int by = (int)floorf((v1 + 1.0f) * 10.0f); by = by < 0 ? 0 : (by > 19 ? 19 : by);
  const int bid = by * NB1D + bx;
  binid[i] = bid;
  rec[i * 2]     = make_float4(v0, v1, y[0], y[1]);
  rec[i * 2 + 1] = make_float4(y[2], y[3], ci, __int_as_float(i));
  atomicAdd(&h[bid], 1); /* LDS atomic, order-independent count */
  __syncthreads();

  bhistT[t * NPREP + blockIdx.x] = h[t];
  if (t + 256 < NBINS) bhistT[(t + 256) * NPREP + blockIdx.x] = h[t + 256];
}

// ---------------------------------------------------------------- K2 ------
// scan + stable scatter, one wave per bin (100 blocks x 4 waves). Each wave
// derives binstart[b] itself from bhistT (int4 loads + wave reduce), writes
// binstart, then scans binid[] in index order; ballot + prefix-popcount gives
// the stable rank. Deterministic.
__global__ __launch_bounds__(256) void scatter_kernel(
    const int* __restrict__ binid, const int* __restrict__ bhistT,
    const float4* __restrict__ rec, float4* __restrict__ srec,
    int* __restrict__ binstart)
{
  const int lane = threadIdx.x & 63, wave = threadIdx.x >> 6;
  const int b = blockIdx.x * 4 + wave;

  int accLT = 0, accEQ = 0;
#pragma unroll
  for (int k = 0; k < 7; ++k) {
    int idx = k * 64 + lane;
    if (idx < NBINS && idx <= b) {
      const int4* hp = (const int4*)(bhistT + idx * NPREP);
      int s = 0;
#pragma unroll
      for (int q = 0; q < NPREP / 4; ++q) {
        int4 v = hp[q];
        s += v.x + v.y + v.z + v.w;
      }
      if (idx < b) accLT += s; else accEQ = s;
    }
  }
  WRED(accLT); WRED(accEQ);
  if (lane == 0) {
    binstart[b] = accLT;
    if (b == NBINS - 1) binstart[NBINS] = accLT + accEQ;
  }
  if (accEQ == 0) return;

  int rank = accLT;
  for (int c = 0; c < NPART; c += 256) {
    int i0 = binid[c + lane];
    int i1 = binid[c + 64 + lane];
    int i2 = binid[c + 128 + lane];
    int i3 = binid[c + 192 + lane];
#define STEP(II, CC) { \
      unsigned long long m = __ballot((II) == b); \
      if ((II) == b) { \
        int my = rank + __popcll(m & ((1ull << lane) - 1ull)); \
        srec[my * 2]     = rec[((CC) + lane) * 2]; \
        srec[my * 2 + 1] = rec[((CC) + lane) * 2 + 1]; \
      } \
      rank += __popcll(m); }
    STEP(i0, c) STEP(i1, c + 64) STEP(i2, c + 128) STEP(i3, c + 192)
#undef STEP
  }
}

// ---------------------------------------------------------------- K3 ------
// sweep. One wave per sorted slot (8192 waves, co-resident at 8 waves/SIMD).
// Candidates = 3 contiguous sorted segments (3x3 bins, bounds prefetched
// together). Self excluded via index compare. dist2 in the reference's
// non-contracted mul/mul/add form. NO device fences / tickets (R5 lesson:
// 2048 __threadfence()s cost ~40us on multi-XCD gfx950) -- cross-block
// ordering is done by the next kernel launch instead.
__global__ __launch_bounds__(256, 8) void sweep_kernel(
    const float* __restrict__ x, const float* __restrict__ wself,
    const float* __restrict__ bvec, const int* __restrict__ binstart,
    const float4* __restrict__ srec, float* __restrict__ out,
    float* __restrict__ partials)
{
  __shared__ float s_scal[4][6];
  const int lane = threadIdx.x & 63, wave = threadIdx.x >> 6;
  const int s = blockIdx.x * 4 + wave;
  const float4 r0 = srec[s * 2];
  const float4 r1 = srec[s * 2 + 1];
  const float px = r0.x, py = r0.y, ci = r1.z;
  const int orig = __float_as_int(r1.w);
  int bx = (int)floorf((px + 1.0f) * 10.0f); bx = bx < 0 ? 0 : (bx > 19 ? 19 : bx);
  int by = (int)floorf((py + 1.0f) * 10.0f); by = by < 0 ? 0 : (by > 19 ? 19 : by);
  const int xlo = (bx > 0) ? bx - 1 : 0, xhi = (bx < 19) ? bx + 1 : 19;
  const int rm = by - 1, rp = by + 1;
  const int b0 = (rm >= 0) ? binstart[rm * NB1D + xlo] : 0;
  const int e0 = (rm >= 0) ? binstart[rm * NB1D + xhi + 1] : 0;
  const int b1 = binstart[by * NB1D + xlo];
  const int e1 = binstart[by * NB1D + xhi + 1];
  const int b2 = (rp < NB1D) ? binstart[rp * NB1D + xlo] : 0;
  const int e2 = (rp < NB1D) ? binstart[rp * NB1D + xhi + 1] : 0;

  float nsx = 0.f, nsy = 0.f, nsz = 0.f, nsw = 0.f;
  float cntR = 0.f, cnbR = 0.f, consCR = 0.f;

#pragma unroll
  for (int seg = 0; seg < 3; ++seg) {
    const int beg = (seg == 0) ? b0 : (seg == 1) ? b1 : b2;
    const int end = (seg == 0) ? e0 : (seg == 1) ? e1 : e2;
    for (int c = beg; c < end; c += 64) {
      int idx = c + lane;
      bool inr = idx < end;
      int ia = inr ? idx : beg;
      float4 a0 = srec[ia * 2];
      float4 a1 = srec[ia * 2 + 1];
      float dx = __fsub_rn(px, a0.x), dy = __fsub_rn(py, a0.y);
      float d2 = __fadd_rn(__fmul_rn(dx, dx), __fmul_rn(dy, dy));
      bool valid = inr && (__float_as_int(a1.w) != orig);
      bool inCR = valid && (d2 < CR2c);
      bool inR  = valid && (d2 < R2c);
      float cj = a1.z;
      consCR += inCR ? cj : 0.f;
      cntR += inR ? 1.f : 0.f;
      cnbR += inR ? cj : 0.f;
      nsx += inR ? a0.z : 0.f;
      nsy += inR ? a0.w : 0.f;
      nsz += inR ? a1.x : 0.f;
      nsw += inR ? a1.y : 0.f;
    }
  }

  WRED(nsx); WRED(nsy); WRED(nsz); WRED(nsw);
  WRED(cntR); WRED(cnbR); WRED(consCR);

  if (lane == 0) {
    const float* xi = x + orig * 7;
    float vx = xi[2], vy = xi[3], typ = xi[4], x5 = xi[5], x6 = xi[6];
    float h0 = bvec[0] + px * wself[0] + py * wself[4] + vx * wself[8] +
               vy * wself[12] + typ * wself[16] + x5 * wself[20] +
               x6 * wself[24] + nsx;
    float h1 = bvec[1] + px * wself[1] + py * wself[5] + vx * wself[9] +
               vy * wself[13] + typ * wself[17] + x5 * wself[21] +
               x6 * wself[25] + nsy;
    float h2 = bvec[2] + px * wself[2] + py * wself[6] + vx * wself[10] +
               vy * wself[14] + typ * wself[18] + x5 * wself[22] +
               x6 * wself[26] + nsz;
    float h3 = bvec[3] + px * wself[3] + py * wself[7] + vx * wself[11] +
               vy * wself[15] + typ * wself[19] + x5 * wself[23] +
               x6 * wself[27] + nsw;
    float scm = ACCS * ci;
    h0 *= scm; h1 *= scm; h2 *= scm; h3 *= scm;
    float nvx = fminf(fmaxf(vx + h0, -MAXV), MAXV);
    float nvy = fminf(fmaxf(vy + h1, -MAXV), MAXV);
    float npx = px + nvx, npy = py + nvy;
    float border = 0.f;
    float ax = fabsf(npx), ay = fabsf(npy);
    if (ax > 1.0f) border += logf(ax + EPSV);
    if (ay > 1.0f) border += logf(ay + EPSV);
    bool dead = (ci > 0.5f) && (cnbR < 2.5f);
    bool consumed = (ci < 0.5f) && (consCR > 4.5f);
    float keep = (dead || consumed) ? 0.f : 1.f;
    float* orow = out + (size_t)orig * 7;
    orow[0] = npx * keep; orow[1] = npy * keep;
    orow[2] = nvx * keep; orow[3] = nvy * keep;
    orow[4] = typ * keep; orow[5] = h2 * keep; orow[6] = h3 * keep;
    s_scal[wave][0] = fabsf(nvx);
    s_scal[wave][1] = fabsf(nvy);
    s_scal[wave][2] = border;
    s_scal[wave][3] = consumed ? 1.f : 0.f;
    s_scal[wave][4] = dead ? 1.f : 0.f;
    s_scal[wave][5] = cntR - cnbR;
  }
  __syncthreads();
  if (threadIdx.x == 0) {
#pragma unroll
    for (int k = 0; k < 6; ++k)
      partials[blockIdx.x * 6 + k] =
          s_scal[0][k] + s_scal[1][k] + s_scal[2][k] + s_scal[3][k];
  }
}

// ---------------------------------------------------------------- K4 ------
// Deterministic reduction of the 2048x6 partials in fixed lane-strided
// order. Separate launch = cross-block visibility without fences.
__global__ __launch_bounds__(384) void reduce_kernel(
    const float* __restrict__ partials, float* __restrict__ out)
{
  int wave = threadIdx.x >> 6, lane = threadIdx.x & 63;
  if (wave >= 6) return;
  float s = 0.f;
  for (int bidx = lane; bidx < SWBLK; bidx += 64) s += partials[bidx * 6 + wave];
  WRED(s);
  if (lane == 0) {
    float v = s;
    if (wave < 2) v = s * (1.0f / 8192.0f); /* vel_bonus = mean */
    out[OUT_SCALARS + wave] = v;
  }
}

// ------------------------------------------------------------- launch -----
extern "C" void kernel_launch(void* const* d_in, const int* in_sizes, int n_in,
                              void* d_out, int out_size, void* d_ws, size_t ws_size,
                              hipStream_t stream)
{
  const float* x      = (const float*)d_in[0];
  const float* wself  = (const float*)d_in[1];
  const float* wneigh = (const float*)d_in[2];
  const float* bvec   = (const float*)d_in[3];
  float* out = (float*)d_out;
  float* ws  = (float*)d_ws;

  float4* rec   = (float4*)ws;                      /* 8N floats          */
  float4* srec  = (float4*)(ws + 8 * NPART);        /* 8N floats          */
  int* binid    = (int*)(ws + 16 * NPART);          /* N ints             */
  int* bhistT   = (int*)(ws + 17 * NPART);          /* NBINS*NPREP ints   */
  int* binstart = bhistT + NBINS * NPREP;           /* NBINS+1 ints       */
  float* partials = (float*)(binstart + NBINS + 65);/* SWBLK*6 floats     */

  hipLaunchKernelGGL(prep_kernel, dim3(NPART / 256), dim3(256), 0, stream,
                     x, wneigh, rec, binid, bhistT);
  hipLaunchKernelGGL(scatter_kernel, dim3(NBINS / 4), dim3(256), 0, stream,
                     binid, bhistT, rec, srec, binstart);
  hipLaunchKernelGGL(sweep_kernel, dim3(SWBLK), dim3(256), 0, stream,
                     x, wself, bvec, binstart, srec, out, partials);
  hipLaunchKernelGGL(reduce_kernel, dim3(1), dim3(384), 0, stream,
                     partials, out);
}

// Round 7
// 44.177 us; speedup vs baseline: 2.1502x; 1.1171x over previous
//
#include <hip/hip_runtime.h>
#include <math.h>

#define NPART 8192
#define R2c   0.0025f     /* RADIUS^2 (float32(0.05^2)) */
#define CR2c  0.01f       /* (2*RADIUS)^2 */
#define ACCS  0.005f
#define MAXV  0.05f
#define EPSV  1e-06f
#define NB1D  20          /* bins per axis, width 0.1 over [-1,1] */
#define NBINS 400
#define NPREP 32          /* prep blocks (per-block histograms) */
#define NSEG  8           /* scatter segments per bin (1024 rows each) */
#define SWBLK 2048        /* sweep blocks: 4 waves = 4 sorted slots each */
#define OUT_SCALARS 57344 /* offset of the 6 scalar outputs in d_out */

#define WRED(v) do { \
    v += __shfl_xor(v, 32); v += __shfl_xor(v, 16); v += __shfl_xor(v, 8); \
    v += __shfl_xor(v, 4);  v += __shfl_xor(v, 2);  v += __shfl_xor(v, 1); \
  } while (0)

// ---------------------------------------------------------------- K1 ------
// prep + per-block histogram. Per row: 32B record {px,py,y0,y1|y2,y3,ci,orig}
// + bin id. Each block LDS-histograms its 256 rows and writes the transposed
// per-block counts bhistT[bin*32+blk] (every entry written -> no zero pass,
// no global atomics, fully deterministic).
__global__ __launch_bounds__(256) void prep_kernel(
    const float* __restrict__ x, const float* __restrict__ wn,
    float4* __restrict__ rec, int* __restrict__ binid,
    int* __restrict__ bhistT)
{
  __shared__ int h[NBINS];
  const int t = threadIdx.x;
  h[t] = 0;
  if (t + 256 < NBINS) h[t + 256] = 0;
  __syncthreads();

  const int i = blockIdx.x * 256 + t;
  const float* xi = x + i * 7;
  float v0 = xi[0], v1 = xi[1], v2 = xi[2], v3 = xi[3];
  float v4 = xi[4], v5 = xi[5], v6 = xi[6];
  float ci = (v4 > 0.5f) ? 1.0f : 0.0f;
  float y[4];
#pragma unroll
  for (int c = 0; c < 4; ++c) {
    float s = v0 * wn[c];
    s += v1 * wn[4 + c];
    s += v2 * wn[8 + c];
    s += v3 * wn[12 + c];
    s += v4 * wn[16 + c];
    s += v5 * wn[20 + c];
    s += v6 * wn[24 + c];
    y[c] = s;
  }
  int bx = (int)floorf((v0 + 1.0f) * 10.0f); bx = bx < 0 ? 0 : (bx > 19 ? 19 : bx);
  int by = (int)floorf((v1 + 1.0f) * 10.0f); by = by < 0 ? 0 : (by > 19 ? 19 : by);
  const int bid = by * NB1D + bx;
  binid[i] = bid;
  rec[i * 2]     = make_float4(v0, v1, y[0], y[1]);
  rec[i * 2 + 1] = make_float4(y[2], y[3], ci, __int_as_float(i));
  atomicAdd(&h[bid], 1); /* LDS atomic, order-independent count */
  __syncthreads();

  bhistT[t * NPREP + blockIdx.x] = h[t];
  if (t + 256 < NBINS) bhistT[(t + 256) * NPREP + blockIdx.x] = h[t + 256];
}

// ---------------------------------------------------------------- K2 ------
// scan + stable scatter, 8 segment-waves per bin (3200 waves, 800 blocks) --
// R6 lesson: 400 waves (1/SIMD) scanning 32 cold-L2 chunks each was ~15us of
// exposed latency. Wave (b,q) derives its start rank from bhistT: rank =
// sum(bins<b, all 32 prep-blocks) + sum(bin b, prep-blocks < 4q), then scans
// only segment q (1024 rows, 4 chunk iters). Stable order preserved ->
// identical sorted layout, fully deterministic.
__global__ __launch_bounds__(256) void scatter_kernel(
    const int* __restrict__ binid, const int* __restrict__ bhistT,
    const float4* __restrict__ rec, float4* __restrict__ srec,
    int* __restrict__ binstart)
{
  const int lane = threadIdx.x & 63, wave = threadIdx.x >> 6;
  const int gw = blockIdx.x * 4 + wave;
  const int b = gw >> 3;   /* bin       */
  const int q = gw & 7;    /* segment   */

  int accLT = 0, accEQpre = 0, accEQfull = 0, accSeg = 0;
#pragma unroll
  for (int k = 0; k < 7; ++k) {
    int idx = k * 64 + lane;
    if (idx < NBINS && idx <= b) {
      const int4* hp = (const int4*)(bhistT + idx * NPREP);
      int sAll = 0, sPre = 0, sSeg = 0;
#pragma unroll
      for (int m = 0; m < 8; ++m) {  /* int4 m = prep-blocks 4m..4m+3 = seg m */
        int4 v = hp[m];
        int sm = v.x + v.y + v.z + v.w;
        sAll += sm;
        sPre += (m < q) ? sm : 0;
        sSeg += (m == q) ? sm : 0;
      }
      if (idx < b) accLT += sAll;
      else { accEQpre = sPre; accEQfull = sAll; accSeg = sSeg; }
    }
  }
  WRED(accLT); WRED(accEQpre); WRED(accEQfull); WRED(accSeg);

  if (q == 0 && lane == 0) {
    binstart[b] = accLT;
    if (b == NBINS - 1) binstart[NBINS] = accLT + accEQfull;
  }
  if (accSeg == 0) return;

  int rank = accLT + accEQpre;
  const int cbeg = q * 1024;
  for (int c = cbeg; c < cbeg + 1024; c += 256) {
    int i0 = binid[c + lane];
    int i1 = binid[c + 64 + lane];
    int i2 = binid[c + 128 + lane];
    int i3 = binid[c + 192 + lane];
#define STEP(II, CC) { \
      unsigned long long m = __ballot((II) == b); \
      if ((II) == b) { \
        int my = rank + __popcll(m & ((1ull << lane) - 1ull)); \
        srec[my * 2]     = rec[((CC) + lane) * 2]; \
        srec[my * 2 + 1] = rec[((CC) + lane) * 2 + 1]; \
      } \
      rank += __popcll(m); }
    STEP(i0, c) STEP(i1, c + 64) STEP(i2, c + 128) STEP(i3, c + 192)
#undef STEP
  }
}

// ---------------------------------------------------------------- K3 ------
// sweep. One wave per sorted slot (8192 waves, co-resident at 8 waves/SIMD).
// R6 lesson: three sequential 1-chunk segment loops exposed ~5 load
// latencies. Now: one unified ordinal loop over all 3 segments (per-lane
// 2-select index map), rolling prefetch of the NEXT chunk's srec before
// processing the current -> one exposed latency. Self excluded via index
// compare. dist2 in the reference's non-contracted mul/mul/add form.
__global__ __launch_bounds__(256, 8) void sweep_kernel(
    const float* __restrict__ x, const float* __restrict__ wself,
    const float* __restrict__ bvec, const int* __restrict__ binstart,
    const float4* __restrict__ srec, float* __restrict__ out,
    float* __restrict__ partials)
{
  __shared__ float s_scal[4][6];
  const int lane = threadIdx.x & 63, wave = threadIdx.x >> 6;
  const int s = blockIdx.x * 4 + wave;
  const float4 r0 = srec[s * 2];
  const float4 r1 = srec[s * 2 + 1];
  const float px = r0.x, py = r0.y, ci = r1.z;
  const int orig = __float_as_int(r1.w);
  int bx = (int)floorf((px + 1.0f) * 10.0f); bx = bx < 0 ? 0 : (bx > 19 ? 19 : bx);
  int by = (int)floorf((py + 1.0f) * 10.0f); by = by < 0 ? 0 : (by > 19 ? 19 : by);
  const int xlo = (bx > 0) ? bx - 1 : 0, xhi = (bx < 19) ? bx + 1 : 19;
  const int rm = by - 1, rp = by + 1;
  const int b0 = (rm >= 0) ? binstart[rm * NB1D + xlo] : 0;
  const int e0 = (rm >= 0) ? binstart[rm * NB1D + xhi + 1] : 0;
  const int b1 = binstart[by * NB1D + xlo];
  const int e1 = binstart[by * NB1D + xhi + 1];
  const int b2 = (rp < NB1D) ? binstart[rp * NB1D + xlo] : 0;
  const int e2 = (rp < NB1D) ? binstart[rp * NB1D + xhi + 1] : 0;
  const int len0 = e0 - b0, len1 = e1 - b1;
  const int total = len0 + len1 + (e2 - b2);

  /* ordinal o -> sorted index (2 selects; lens are wave-uniform) */
#define IA(O, DST) { int t1 = (O) - len0, t2 = (O) - len0 - len1; \
    DST = b0 + (O); DST = (t1 >= 0) ? (b1 + t1) : DST; \
    DST = (t2 >= 0) ? (b2 + t2) : DST; }

  float nsx = 0.f, nsy = 0.f, nsz = 0.f, nsw = 0.f;
  float cntR = 0.f, cnbR = 0.f, consCR = 0.f;

  int o = lane;
  bool v = o < total;
  int ia; IA(v ? o : 0, ia); if (!v) ia = 0;
  float4 a0 = srec[ia * 2];
  float4 a1 = srec[ia * 2 + 1];
  const int nchunk = (total + 63) >> 6;
  for (int k = 0; k < nchunk; ++k) {
    int on = o + 64;
    bool vn = on < total;
    int ian; IA(vn ? on : 0, ian); if (!vn) ian = 0;
    float4 n0 = srec[ian * 2];          /* prefetch next chunk */
    float4 n1 = srec[ian * 2 + 1];
    float dx = __fsub_rn(px, a0.x), dy = __fsub_rn(py, a0.y);
    float d2 = __fadd_rn(__fmul_rn(dx, dx), __fmul_rn(dy, dy));
    bool valid = v && (__float_as_int(a1.w) != orig);
    bool inCR = valid && (d2 < CR2c);
    bool inR  = valid && (d2 < R2c);
    float cj = a1.z;
    consCR += inCR ? cj : 0.f;
    cntR += inR ? 1.f : 0.f;
    cnbR += inR ? cj : 0.f;
    nsx += inR ? a0.z : 0.f;
    nsy += inR ? a0.w : 0.f;
    nsz += inR ? a1.x : 0.f;
    nsw += inR ? a1.y : 0.f;
    o = on; v = vn; a0 = n0; a1 = n1;
  }
#undef IA

  WRED(nsx); WRED(nsy); WRED(nsz); WRED(nsw);
  WRED(cntR); WRED(cnbR); WRED(consCR);

  if (lane == 0) {
    const float* xi = x + orig * 7;
    float vx = xi[2], vy = xi[3], typ = xi[4], x5 = xi[5], x6 = xi[6];
    float h0 = bvec[0] + px * wself[0] + py * wself[4] + vx * wself[8] +
               vy * wself[12] + typ * wself[16] + x5 * wself[20] +
               x6 * wself[24] + nsx;
    float h1 = bvec[1] + px * wself[1] + py * wself[5] + vx * wself[9] +
               vy * wself[13] + typ * wself[17] + x5 * wself[21] +
               x6 * wself[25] + nsy;
    float h2 = bvec[2] + px * wself[2] + py * wself[6] + vx * wself[10] +
               vy * wself[14] + typ * wself[18] + x5 * wself[22] +
               x6 * wself[26] + nsz;
    float h3 = bvec[3] + px * wself[3] + py * wself[7] + vx * wself[11] +
               vy * wself[15] + typ * wself[19] + x5 * wself[23] +
               x6 * wself[27] + nsw;
    float scm = ACCS * ci;
    h0 *= scm; h1 *= scm; h2 *= scm; h3 *= scm;
    float nvx = fminf(fmaxf(vx + h0, -MAXV), MAXV);
    float nvy = fminf(fmaxf(vy + h1, -MAXV), MAXV);
    float npx = px + nvx, npy = py + nvy;
    float border = 0.f;
    float ax = fabsf(npx), ay = fabsf(npy);
    if (ax > 1.0f) border += logf(ax + EPSV);
    if (ay > 1.0f) border += logf(ay + EPSV);
    bool dead = (ci > 0.5f) && (cnbR < 2.5f);
    bool consumed = (ci < 0.5f) && (consCR > 4.5f);
    float keep = (dead || consumed) ? 0.f : 1.f;
    float* orow = out + (size_t)orig * 7;
    orow[0] = npx * keep; orow[1] = npy * keep;
    orow[2] = nvx * keep; orow[3] = nvy * keep;
    orow[4] = typ * keep; orow[5] = h2 * keep; orow[6] = h3 * keep;
    s_scal[wave][0] = fabsf(nvx);
    s_scal[wave][1] = fabsf(nvy);
    s_scal[wave][2] = border;
    s_scal[wave][3] = consumed ? 1.f : 0.f;
    s_scal[wave][4] = dead ? 1.f : 0.f;
    s_scal[wave][5] = cntR - cnbR;
  }
  __syncthreads();
  if (threadIdx.x == 0) {
#pragma unroll
    for (int k = 0; k < 6; ++k)
      partials[blockIdx.x * 6 + k] =
          s_scal[0][k] + s_scal[1][k] + s_scal[2][k] + s_scal[3][k];
  }
}

// ---------------------------------------------------------------- K4 ------
// Deterministic reduction of the 2048x6 partials in fixed lane-strided
// order. Separate launch = cross-block visibility without fences (R5 lesson:
// no per-block device fences on multi-XCD gfx950).
__global__ __launch_bounds__(384) void reduce_kernel(
    const float* __restrict__ partials, float* __restrict__ out)
{
  int wave = threadIdx.x >> 6, lane = threadIdx.x & 63;
  if (wave >= 6) return;
  float s = 0.f;
  for (int bidx = lane; bidx < SWBLK; bidx += 64) s += partials[bidx * 6 + wave];
  WRED(s);
  if (lane == 0) {
    float v = s;
    if (wave < 2) v = s * (1.0f / 8192.0f); /* vel_bonus = mean */
    out[OUT_SCALARS + wave] = v;
  }
}

// ------------------------------------------------------------- launch -----
extern "C" void kernel_launch(void* const* d_in, const int* in_sizes, int n_in,
                              void* d_out, int out_size, void* d_ws, size_t ws_size,
                              hipStream_t stream)
{
  const float* x      = (const float*)d_in[0];
  const float* wself  = (const float*)d_in[1];
  const float* wneigh = (const float*)d_in[2];
  const float* bvec   = (const float*)d_in[3];
  float* out = (float*)d_out;
  float* ws  = (float*)d_ws;

  float4* rec   = (float4*)ws;                      /* 8N floats          */
  float4* srec  = (float4*)(ws + 8 * NPART);        /* 8N floats          */
  int* binid    = (int*)(ws + 16 * NPART);          /* N ints             */
  int* bhistT   = (int*)(ws + 17 * NPART);          /* NBINS*NPREP ints   */
  int* binstart = bhistT + NBINS * NPREP;           /* NBINS+1 ints       */
  float* partials = (float*)(binstart + NBINS + 65);/* SWBLK*6 floats     */

  hipLaunchKernelGGL(prep_kernel, dim3(NPART / 256), dim3(256), 0, stream,
                     x, wneigh, rec, binid, bhistT);
  hipLaunchKernelGGL(scatter_kernel, dim3(NBINS * NSEG / 4), dim3(256), 0, stream,
                     binid, bhistT, rec, srec, binstart);
  hipLaunchKernelGGL(sweep_kernel, dim3(SWBLK), dim3(256), 0, stream,
                     x, wself, bvec, binstart, srec, out, partials);
  hipLaunchKernelGGL(reduce_kernel, dim3(1), dim3(384), 0, stream,
                     partials, out);
}